// Round 2
// baseline (189.005 us; speedup 1.0000x reference)
//
#include <hip/hip_runtime.h>
#include <math.h>

// DigitCaps dynamic routing, MI355X. Round 9: split each (b,j) across 2 waves.
//
// Round-8 post-mortem: killing staging VALU + bank conflicts (conflicts 2.3M->0,
// FETCH 72->8.5 MB) left dur flat at 93.7 us; VALUBusy fell 58->49%, occupancy
// 29->22.7%. => latency-bound on the per-wave serial chain (14 k-slots of
// dependent fdot2/exp/fma + 26 six-deep shfl chains) at only ~6 waves/SIMD
// (VGPR=80).
//
// Round 9: two waves co-own one (b,j), parity-interleaved k-slots (wave h
// takes k = 2m+h, m=0..6). uh shrinks 56->28 VGPRs (target <=64 total ->
// 8 waves/SIMD occupancy step); per-wave serial work halves; grid doubles to
// 5312 blocks. Per-iteration cross-wave combine: wave_sum (fp32, same order)
// -> 9 floats through LDS -> both waves add halves; 1 barrier per iteration.
// Staging unchanged: prepacked fp16 W chunks via global_load_lds width=16
// (zero staging VALU, linear LDS, no bank conflicts).

#define BB 128
#define JJ 166
#define RR 864
#define OO 8
#define WP_U2 (JJ * 7168)  // W fp16: per j: 3*2048 + 1024 = 7168 uint2 (57,344 B)
#define UP_U2 (BB * 896)   // u fp16: [b][896] uint2, routes >=864 zeroed

typedef __fp16 h2v __attribute__((ext_vector_type(2)));

__device__ __forceinline__ uint32_t pack2(float a, float b) {
    return __builtin_bit_cast(uint32_t, __builtin_amdgcn_cvt_pkrtz(a, b));
}
__device__ __forceinline__ h2v bc_h2(uint32_t u) {
    return __builtin_bit_cast(h2v, u);
}
__device__ __forceinline__ float lo_f(uint32_t u) {
    return (float)__builtin_bit_cast(h2v, u).x;
}
__device__ __forceinline__ float hi_f(uint32_t u) {
    return (float)__builtin_bit_cast(h2v, u).y;
}

__device__ __forceinline__ float wave_sum(float v) {
#pragma unroll
    for (int m = 32; m >= 1; m >>= 1) v += __shfl_xor(v, m, 64);
    return v;
}

// ---- pre-pass: W f32 [J][R][O][4] -> Wp fp16 chunk-major; u -> uP fp16 ----
__global__ __launch_bounds__(256) void prepack_kernel(
    const float* __restrict__ u, const float* __restrict__ W,
    uint2* __restrict__ ws) {
    const int t = threadIdx.x;
    const int bid = blockIdx.x;
    if (bid < JJ * 4) {
        const int j = bid >> 2;
        const int c = bid & 3;
        const float4* __restrict__ W4 = (const float4*)W;  // [(j*864+r)*8+o]
        uint2* __restrict__ dst = ws + (size_t)j * 7168 + c * 2048;
        if (c < 3) {
            // 2048 elems = [o=i][rl=t]; the 8 i's per thread hit one 128B line
#pragma unroll
            for (int i = 0; i < 8; ++i) {
                const int r = c * 256 + t;
                const float4 w = W4[((size_t)j * RR + r) * 8 + i];
                dst[i * 256 + t] = make_uint2(pack2(w.x, w.y), pack2(w.z, w.w));
            }
        } else {
            // 1024 elems = [o][rl], rl in [0,128), routes >= 864 zeroed
#pragma unroll
            for (int i = 0; i < 4; ++i) {
                const int e = i * 256 + t;
                const int o = e >> 7;
                const int rl = e & 127;
                float4 w = make_float4(0.f, 0.f, 0.f, 0.f);
                if (rl < 96) w = W4[((size_t)j * RR + 768 + rl) * 8 + o];
                dst[e] = make_uint2(pack2(w.x, w.y), pack2(w.z, w.w));
            }
        }
    } else {
        // u pack: e in [0, 128*896)
        const int e = (bid - JJ * 4) * 256 + t;
        const int b = e / 896;
        const int r = e - b * 896;
        const float4* __restrict__ u4 = (const float4*)u;
        float4 uu = make_float4(0.f, 0.f, 0.f, 0.f);
        if (r < RR) uu = u4[(size_t)b * RR + r];
        ws[WP_U2 + e] = make_uint2(pack2(uu.x, uu.y), pack2(uu.z, uu.w));
    }
}

__global__ __launch_bounds__(512) void digitcaps_kernel(
    const uint2* __restrict__ Wp, const uint2* __restrict__ uP,
    float* __restrict__ out) {
    const int tid = threadIdx.x;
    const int lane = tid & 63;
    const int wave = tid >> 6;
    const int pair = wave >> 1;  // 0..3: which b within the block
    const int h = wave & 1;      // half: k-slot parity

    // XCD-bijective swizzle: 5312 blocks = 8 XCDs x 664. The 32 same-j blocks
    // become consecutive on one XCD -> Wp[j] (56 KB) L2-hot.
    int bid = blockIdx.x;
    bid = (bid & 7) * 664 + (bid >> 3);
    const int j = bid >> 5;
    const int b = ((bid & 31) << 2) + pair;

    // two W buffers, each [o][rl] uint2, linear (global_load_lds order): 32,768 B
    __shared__ uint2 wlds[2][2048];
    // cross-wave combine scratch: [iter][pair][half][12 floats] = 1,152 B
    __shared__ float xch[3][4][2][12];

    const uint2* __restrict__ uPb = uP + (size_t)b * 896;

    uint32_t uh[7][4];  // this wave's 7 k-slots (k = 2m+h); constant-indexed

    // ---- stage chunk CC into LDS buffer BUF via async global->LDS, 16 B/lane ----
#define STAGE(CC, BUF, ROUNDS)                                                 \
    {                                                                          \
        const char* gsrc =                                                     \
            (const char*)(Wp + (size_t)j * 7168 + (CC) * 2048);                \
        _Pragma("unroll")                                                      \
        for (int i = 0; i < (ROUNDS); ++i) {                                   \
            __builtin_amdgcn_global_load_lds(                                  \
                (const __attribute__((address_space(1))) uint32_t*)            \
                    (gsrc + i * 8192 + tid * 16),                              \
                (__attribute__((address_space(3))) uint32_t*)                  \
                    ((char*)(&wlds[BUF][0]) + i * 8192 + (wave << 10)),        \
                16, 0, 0);                                                     \
        }                                                                      \
    }

    // ---- u_hat for chunk CC: this wave's TT slots (t=0..TT-1, m=2*CC+t,
    //      within-chunk slot 2t+h). Zero-padding kills all route guards. ----
#define COMPUTE(CC, BUF, TT, STRIDE)                                           \
    {                                                                          \
        _Pragma("unroll")                                                      \
        for (int t = 0; t < (TT); ++t) {                                       \
            const int m = 2 * (CC) + t;                                        \
            const int rl = ((2 * t + h) << 6) + lane;                          \
            const uint2 up = uPb[(CC) * 256 + rl];                             \
            float d[OO];                                                       \
            _Pragma("unroll")                                                  \
            for (int o = 0; o < OO; ++o) {                                     \
                const uint2 ww = wlds[BUF][o * (STRIDE) + rl];                 \
                float t0 = __builtin_amdgcn_fdot2(bc_h2(ww.x), bc_h2(up.x),    \
                                                  0.0f, false);                \
                d[o] = __builtin_amdgcn_fdot2(bc_h2(ww.y), bc_h2(up.y), t0,    \
                                              false);                         \
            }                                                                  \
            _Pragma("unroll")                                                  \
            for (int o2 = 0; o2 < 4; ++o2)                                     \
                uh[m][o2] = pack2(d[2 * o2], d[2 * o2 + 1]);                   \
        }                                                                      \
    }

    // chunks 0-2: 16,384 B (2 rounds); chunk 3: 8,192 B (1 round, stride 128)
    STAGE(0, 0, 2)
    __syncthreads();
    STAGE(1, 1, 2)        // loads fly while computing chunk 0
    COMPUTE(0, 0, 2, 256)
    __syncthreads();
    STAGE(2, 0, 2)
    COMPUTE(1, 1, 2, 256)
    __syncthreads();
    STAGE(3, 1, 1)
    COMPUTE(2, 0, 2, 256)
    __syncthreads();
    COMPUTE(3, 1, 1, 128)
#undef STAGE
#undef COMPUTE

    // ---- cross-wave combine: arr[0..N-1] broadcast per-lane after wave_sum;
    //      exchange through LDS, both waves end with the pair-wide sums. ----
#define XCHG(IT, NV, arr)                                                      \
    {                                                                          \
        float wv = 0.0f;                                                       \
        _Pragma("unroll")                                                      \
        for (int q = 0; q < (NV); ++q)                                         \
            if (lane == q) wv = arr[q];                                        \
        if (lane < (NV)) xch[IT][pair][h][lane] = wv;                          \
        __syncthreads();                                                       \
        _Pragma("unroll")                                                      \
        for (int q = 0; q < (NV); ++q) arr[q] += xch[IT][pair][1 - h][q];      \
    }

    float V[OO];  // running sum of past v's (b_r = <uhat_r, V>)
    float v[OO];

    // ---- iteration 0: b=0 -> c uniform = 1/R (packed fp16 partial sums) ----
    {
        h2v accp[4];
#pragma unroll
        for (int o2 = 0; o2 < 4; ++o2) accp[o2] = bc_h2(uh[0][o2]);
#pragma unroll
        for (int m = 1; m < 7; ++m)
#pragma unroll
            for (int o2 = 0; o2 < 4; ++o2) accp[o2] += bc_h2(uh[m][o2]);

        float s[OO];
#pragma unroll
        for (int o2 = 0; o2 < 4; ++o2) {
            s[2 * o2]     = wave_sum((float)accp[o2].x);
            s[2 * o2 + 1] = wave_sum((float)accp[o2].y);
        }
        XCHG(0, 8, s)
        float n2 = 0.0f;
#pragma unroll
        for (int o = 0; o < OO; ++o) {
            s[o] *= (1.0f / (float)RR);
            n2 += s[o] * s[o];
        }
        const float scale = sqrtf(n2) / (1.0f + n2);
#pragma unroll
        for (int o = 0; o < OO; ++o) { v[o] = s[o] * scale; V[o] = v[o]; }
    }

    // ---- iterations 1 and 2 ----
#pragma unroll
    for (int it = 1; it < 3; ++it) {
        // pack V once per iteration for dot2 logits
        uint32_t Vp[4];
#pragma unroll
        for (int o2 = 0; o2 < 4; ++o2)
            Vp[o2] = pack2(V[2 * o2], V[2 * o2 + 1]);

        float sz[9];  // sz[0..7] = sp, sz[8] = zp
#pragma unroll
        for (int q = 0; q < 9; ++q) sz[q] = 0.0f;

#pragma unroll
        for (int m = 0; m < 7; ++m) {
            float br = 0.0f;
#pragma unroll
            for (int o2 = 0; o2 < 4; ++o2)
                br = __builtin_amdgcn_fdot2(bc_h2(uh[m][o2]), bc_h2(Vp[o2]),
                                            br, false);
            // mask invalid routes (h==1, m==6 -> k13, lanes>=32 are padding)
            const float e =
                (m < 6 || h == 0 || lane < 32) ? __expf(br) : 0.0f;
            sz[8] += e;
#pragma unroll
            for (int o2 = 0; o2 < 4; ++o2) {
                sz[2 * o2]     = fmaf(e, lo_f(uh[m][o2]), sz[2 * o2]);
                sz[2 * o2 + 1] = fmaf(e, hi_f(uh[m][o2]), sz[2 * o2 + 1]);
            }
        }
#pragma unroll
        for (int q = 0; q < 9; ++q) sz[q] = wave_sum(sz[q]);
        XCHG(it, 9, sz)

        const float invZ = 1.0f / sz[8];
        float s[OO];
        float n2 = 0.0f;
#pragma unroll
        for (int o = 0; o < OO; ++o) {
            s[o] = sz[o] * invZ;
            n2 += s[o] * s[o];
        }
        const float scale = sqrtf(n2) / (1.0f + n2);
#pragma unroll
        for (int o = 0; o < OO; ++o) v[o] = s[o] * scale;

        if (it < 2) {
#pragma unroll
            for (int o = 0; o < OO; ++o) V[o] += v[o];
        }
    }
#undef XCHG

    // ---- write out[b][j][o]; v replicated across lanes; one wave per pair ----
    if (h == 0) {
        float outv = 0.0f;
#pragma unroll
        for (int o = 0; o < OO; ++o)
            if (lane == o) outv = v[o];
        if (lane < OO) out[(b * JJ + j) * OO + lane] = outv;
    }
}

extern "C" void kernel_launch(void* const* d_in, const int* in_sizes, int n_in,
                              void* d_out, int out_size, void* d_ws, size_t ws_size,
                              hipStream_t stream) {
    const float* u = (const float*)d_in[0];  // [128, 864, 4]
    const float* W = (const float*)d_in[1];  // [1, 166, 864, 8, 4]
    float* out = (float*)d_out;              // [128, 166, 8]
    uint2* ws = (uint2*)d_ws;                // needs (WP_U2 + UP_U2)*8 = ~10.0 MB

    // pre-pass: 664 W-blocks + 448 u-blocks
    prepack_kernel<<<JJ * 4 + (BB * 896) / 256, 256, 0, stream>>>(u, W, ws);

    // main: 166 j * 32 b-groups, 512 threads = 8 waves = 4 (b,j) pairs x 2
    digitcaps_kernel<<<JJ * 32, 512, 0, stream>>>(ws, ws + WP_U2, out);
}

// Round 3
// 162.690 us; speedup vs baseline: 1.1618x; 1.1618x over previous
//
#include <hip/hip_runtime.h>
#include <math.h>

// DigitCaps dynamic routing, MI355X. Round 10: lane=batch transposition.
//
// Round-9 post-mortem: splitting (b,j) across 2 waves regressed (93.7->129us)
// - doubled block count doubled the fixed staging/barrier overhead per unit
// work; occupancy rose (40%) but the structure's overhead dominated. The real
// problem: with lane=route, every reduction is cross-lane (26 six-deep shfl
// chains per (b,j)) and W must be staged to LDS with barriers.
//
// Round 10 restructure:
//  - lane = b (64 batches), wave = 108-route chunk, block = 8 waves = one
//    (j, b-half). Grid 332. Route reductions are now per-lane serial fma
//    chains: ZERO shuffles in the hot loop. Only combine: 8 wave-partials
//    x 12 floats via LDS, 2 barriers/iter (6 total).
//  - W[j,r] is wave-uniform -> s_load into SGPRs (wave id readfirstlane'd
//    so the address is provably uniform). W uses no VGPRs, no LDS, no VMEM:
//    fdot2 reads the halves straight from SGPRs (1 SGPR/VALU op is legal).
//  - u pre-transposed to fp16 uT[r][b]: lane-consecutive 512B coalesced
//    loads, L2-resident (884 KB). W prepacked fp16 [j][r][o][i-pairs].
//  - 864 = 8*108 exactly: no guards, no masks anywhere. u_hat stays f32
//    (more accurate than round-8's fp16 repack; same fp16 input rounding).
//  - routing logit/accum in float2 ops to get v_pk_fma_f32 where possible.

#define BB 128
#define JJ 166
#define RR 864
#define OO 8
#define W_U2 (JJ * RR * 8)  // W fp16: (j*864+r)*8 uint2 = 64 B per route

typedef __fp16 h2v __attribute__((ext_vector_type(2)));
typedef float f32x2 __attribute__((ext_vector_type(2)));

static __device__ __forceinline__ uint32_t pack2(float a, float b) {
    return __builtin_bit_cast(uint32_t, __builtin_amdgcn_cvt_pkrtz(a, b));
}
static __device__ __forceinline__ h2v bc_h2(uint32_t u) {
    return __builtin_bit_cast(h2v, u);
}

// ---- pre-pass: W -> fp16 [j][r][8 o-pairs]; u -> fp16 uT[r][b] ----
__global__ __launch_bounds__(256) void prepack_kernel(
    const float* __restrict__ u, const float* __restrict__ W,
    uint2* __restrict__ ws) {
    const int t = blockIdx.x * 256 + threadIdx.x;
    if (t < JJ * RR) {
        // one (j,r): read 8 float4 (128 B), write 8 uint2 (64 B)
        const float4* __restrict__ W4 = (const float4*)W + (size_t)t * 8;
        uint2* __restrict__ dst = ws + (size_t)t * 8;
#pragma unroll
        for (int o = 0; o < 8; ++o) {
            const float4 wv = W4[o];
            dst[o] = make_uint2(pack2(wv.x, wv.y), pack2(wv.z, wv.w));
        }
    } else {
        const int e = t - JJ * RR;  // e = r*128 + b (coalesced writes)
        if (e < RR * BB) {
            const int r = e >> 7;
            const int b = e & 127;
            const float4 uu = ((const float4*)u)[(size_t)b * RR + r];
            ws[W_U2 + e] = make_uint2(pack2(uu.x, uu.y), pack2(uu.z, uu.w));
        }
    }
}

// 16 fdot2: d2[k].x = o=2k, d2[k].y = o=2k+1 (w0..w3, up in scope)
#define UHAT(D)                                                                \
    {                                                                          \
        float p;                                                               \
        p = __builtin_amdgcn_fdot2(bc_h2(w0.x), bc_h2(up.x), 0.0f, false);     \
        D[0].x = __builtin_amdgcn_fdot2(bc_h2(w0.y), bc_h2(up.y), p, false);   \
        p = __builtin_amdgcn_fdot2(bc_h2(w0.z), bc_h2(up.x), 0.0f, false);     \
        D[0].y = __builtin_amdgcn_fdot2(bc_h2(w0.w), bc_h2(up.y), p, false);   \
        p = __builtin_amdgcn_fdot2(bc_h2(w1.x), bc_h2(up.x), 0.0f, false);     \
        D[1].x = __builtin_amdgcn_fdot2(bc_h2(w1.y), bc_h2(up.y), p, false);   \
        p = __builtin_amdgcn_fdot2(bc_h2(w1.z), bc_h2(up.x), 0.0f, false);     \
        D[1].y = __builtin_amdgcn_fdot2(bc_h2(w1.w), bc_h2(up.y), p, false);   \
        p = __builtin_amdgcn_fdot2(bc_h2(w2.x), bc_h2(up.x), 0.0f, false);     \
        D[2].x = __builtin_amdgcn_fdot2(bc_h2(w2.y), bc_h2(up.y), p, false);   \
        p = __builtin_amdgcn_fdot2(bc_h2(w2.z), bc_h2(up.x), 0.0f, false);     \
        D[2].y = __builtin_amdgcn_fdot2(bc_h2(w2.w), bc_h2(up.y), p, false);   \
        p = __builtin_amdgcn_fdot2(bc_h2(w3.x), bc_h2(up.x), 0.0f, false);     \
        D[3].x = __builtin_amdgcn_fdot2(bc_h2(w3.y), bc_h2(up.y), p, false);   \
        p = __builtin_amdgcn_fdot2(bc_h2(w3.z), bc_h2(up.x), 0.0f, false);     \
        D[3].y = __builtin_amdgcn_fdot2(bc_h2(w3.w), bc_h2(up.y), p, false);   \
    }

#define LOAD_W(T)                                                              \
    const uint4 w0 = *(const uint4*)(Wr + (T) * 16);                           \
    const uint4 w1 = *(const uint4*)(Wr + (T) * 16 + 4);                       \
    const uint4 w2 = *(const uint4*)(Wr + (T) * 16 + 8);                       \
    const uint4 w3 = *(const uint4*)(Wr + (T) * 16 + 12);

__global__ __launch_bounds__(512) void digitcaps_kernel(
    const uint32_t* __restrict__ Wp,  // [(j*864+r)*16] dwords, 64 B per route
    const uint2* __restrict__ uT,     // [r*128 + b]
    float* __restrict__ out) {
    const int tid = threadIdx.x;
    const int l = tid & 63;  // lane = b within half
    // wave id via readfirstlane -> provably uniform -> W loads become s_load
    const int w = __builtin_amdgcn_readfirstlane(tid >> 6);

    // bijective XCD swizzle (332 = 8*41 + 4): same-j block pairs contiguous
    const int orig = blockIdx.x;
    const int xcd = orig & 7;
    const int q = 332 / 8, rm = 332 % 8;
    const int base =
        (xcd < rm) ? xcd * (q + 1) : rm * (q + 1) + (xcd - rm) * q;
    const int bid = base + (orig >> 3);

    const int j = bid >> 1;
    const int b = ((bid & 1) << 6) + l;

    const int r0 = w * 108;  // this wave's route chunk (8*108 = 864 exact)
    const uint32_t* __restrict__ Wr = Wp + ((size_t)j * RR + r0) * 16;
    const uint2* __restrict__ ur = uT + (size_t)r0 * BB + b;

    // cross-wave combine scratch: 8 wave-partials x 64 lanes
    __shared__ float4 xA[8 * 64];  // s[0..3]
    __shared__ float4 xB[8 * 64];  // s[4..7]
    __shared__ float xZ[8 * 64];   // z

    f32x2 V2[4], v2[4];

    // ---- iteration 0: c uniform = 1/R -> s = (sum_r u_hat)/R ----
    {
        f32x2 s2[4];
#pragma unroll
        for (int k = 0; k < 4; ++k) { s2[k].x = 0.f; s2[k].y = 0.f; }
#pragma unroll 2
        for (int t = 0; t < 108; ++t) {
            const uint2 up = ur[t * BB];
            LOAD_W(t)
            f32x2 d2[4];
            UHAT(d2)
#pragma unroll
            for (int k = 0; k < 4; ++k) s2[k] += d2[k];
        }
        xA[w * 64 + l] = make_float4(s2[0].x, s2[0].y, s2[1].x, s2[1].y);
        xB[w * 64 + l] = make_float4(s2[2].x, s2[2].y, s2[3].x, s2[3].y);
        __syncthreads();
        float4 A = xA[l], B = xB[l];
#pragma unroll
        for (int w2i = 1; w2i < 8; ++w2i) {
            const float4 a2 = xA[w2i * 64 + l], b2 = xB[w2i * 64 + l];
            A.x += a2.x; A.y += a2.y; A.z += a2.z; A.w += a2.w;
            B.x += b2.x; B.y += b2.y; B.z += b2.z; B.w += b2.w;
        }
        __syncthreads();
        const float inv = 1.0f / (float)RR;
        f32x2 sc[4];
        sc[0].x = A.x * inv; sc[0].y = A.y * inv;
        sc[1].x = A.z * inv; sc[1].y = A.w * inv;
        sc[2].x = B.x * inv; sc[2].y = B.y * inv;
        sc[3].x = B.z * inv; sc[3].y = B.w * inv;
        float n2 = 0.f;
#pragma unroll
        for (int k = 0; k < 4; ++k) n2 += sc[k].x * sc[k].x + sc[k].y * sc[k].y;
        const float scale = sqrtf(n2) / (1.0f + n2);
#pragma unroll
        for (int k = 0; k < 4; ++k) { v2[k] = sc[k] * scale; V2[k] = v2[k]; }
    }

    // ---- iterations 1 and 2 ----
#pragma unroll
    for (int it = 1; it < 3; ++it) {
        f32x2 sz2[4];
        float z = 0.f;
#pragma unroll
        for (int k = 0; k < 4; ++k) { sz2[k].x = 0.f; sz2[k].y = 0.f; }
#pragma unroll 2
        for (int t = 0; t < 108; ++t) {
            const uint2 up = ur[t * BB];
            LOAD_W(t)
            f32x2 d2[4];
            UHAT(d2)
            // logit b_r = <u_hat, V> (V = running sum of past v's)
            f32x2 lac = d2[0] * V2[0];
            lac += d2[1] * V2[1];
            lac += d2[2] * V2[2];
            lac += d2[3] * V2[3];
            const float br = lac.x + lac.y;
            const float e = __expf(br);
            z += e;
            f32x2 e2; e2.x = e; e2.y = e;
#pragma unroll
            for (int k = 0; k < 4; ++k) sz2[k] += e2 * d2[k];
        }
        xA[w * 64 + l] = make_float4(sz2[0].x, sz2[0].y, sz2[1].x, sz2[1].y);
        xB[w * 64 + l] = make_float4(sz2[2].x, sz2[2].y, sz2[3].x, sz2[3].y);
        xZ[w * 64 + l] = z;
        __syncthreads();
        float4 A = xA[l], B = xB[l];
        float Z = xZ[l];
#pragma unroll
        for (int w2i = 1; w2i < 8; ++w2i) {
            const float4 a2 = xA[w2i * 64 + l], b2 = xB[w2i * 64 + l];
            A.x += a2.x; A.y += a2.y; A.z += a2.z; A.w += a2.w;
            B.x += b2.x; B.y += b2.y; B.z += b2.z; B.w += b2.w;
            Z += xZ[w2i * 64 + l];
        }
        __syncthreads();
        const float invZ = 1.0f / Z;
        f32x2 sc[4];
        sc[0].x = A.x * invZ; sc[0].y = A.y * invZ;
        sc[1].x = A.z * invZ; sc[1].y = A.w * invZ;
        sc[2].x = B.x * invZ; sc[2].y = B.y * invZ;
        sc[3].x = B.z * invZ; sc[3].y = B.w * invZ;
        float n2 = 0.f;
#pragma unroll
        for (int k = 0; k < 4; ++k) n2 += sc[k].x * sc[k].x + sc[k].y * sc[k].y;
        const float scale = sqrtf(n2) / (1.0f + n2);
#pragma unroll
        for (int k = 0; k < 4; ++k) v2[k] = sc[k] * scale;
        if (it == 1) {
#pragma unroll
            for (int k = 0; k < 4; ++k) V2[k] += v2[k];
        }
    }

    // ---- write out[b][j][0..7]; every lane of wave 0 owns one b ----
    if (w == 0) {
        float4* dst = (float4*)(out + ((size_t)b * JJ + j) * OO);
        dst[0] = make_float4(v2[0].x, v2[0].y, v2[1].x, v2[1].y);
        dst[1] = make_float4(v2[2].x, v2[2].y, v2[3].x, v2[3].y);
    }
}

extern "C" void kernel_launch(void* const* d_in, const int* in_sizes, int n_in,
                              void* d_out, int out_size, void* d_ws, size_t ws_size,
                              hipStream_t stream) {
    const float* u = (const float*)d_in[0];  // [128, 864, 4]
    const float* W = (const float*)d_in[1];  // [1, 166, 864, 8, 4]
    float* out = (float*)d_out;              // [128, 166, 8]
    uint2* ws = (uint2*)d_ws;                // needs 10.07 MB (< round-8's 10.44)

    // pre-pass: 166*864 W-routes + 864*128 u-elements, one thread each
    const int total = JJ * RR + RR * BB;
    prepack_kernel<<<(total + 255) / 256, 256, 0, stream>>>(u, W, ws);

    // main: 166 j x 2 b-halves, 512 threads = 8 route-chunk waves
    digitcaps_kernel<<<JJ * 2, 512, 0, stream>>>(
        (const uint32_t*)ws, ((const uint2*)ws) + W_U2, out);
}